// Round 2
// baseline (83.194 us; speedup 1.0000x reference)
//
#include <hip/hip_runtime.h>

#define RAD   3
#define KS    7
#define TILE  16
#define TXD   8                    // threads in x; each covers 2 adjacent pixels
#define TYD   16
#define NTHR  (TXD * TYD)          // 128 threads = 2 waves
#define PADW  (TILE + 2 * RAD)     // 22
#define PADS  23                   // padded row stride (odd mod 8 -> bank spread)
#define NC    16
#define HW    256
#define PLANE (HW * HW)

// w = exp(-mean_c(d^2)/H2) = exp(CEXP * ss), ss = sum_c d^2, H2 = 0.01
#define CEXP   (-6.25f)            // -1/(16*0.01)
#define M2CEXP (12.5f)             // -2*CEXP
#define RATIO  0.2f

#define DOT4(s, n, o) do {            \
    s = fmaf((n).x, (o).x, s);        \
    s = fmaf((n).y, (o).y, s);        \
    s = fmaf((n).z, (o).z, s);        \
    s = fmaf((n).w, (o).w, s); } while (0)

#define ACC4(a, n, w) do {            \
    (a).x = fmaf(w, (n).x, (a).x);    \
    (a).y = fmaf(w, (n).y, (a).y);    \
    (a).z = fmaf(w, (n).z, (a).z);    \
    (a).w = fmaf(w, (n).w, (a).w); } while (0)

__global__ __launch_bounds__(NTHR)
void nlm_kernel(const float* __restrict__ x, float* __restrict__ out)
{
    // channel-plane float4 layout; row stride 23 (odd) so ds_read_b128 lanes
    // spread uniformly over all eight 4-bank groups.
    __shared__ float4 sm[4][PADW][PADS];   // 32384 B
    __shared__ float  smn[PADW][PADS];     // ||pixel||^2 over 16 ch, 2024 B

    const int tx  = threadIdx.x;           // 0..7
    const int ty  = threadIdx.y;           // 0..15
    const int tid = ty * TXD + tx;
    const int bx0 = blockIdx.x * TILE - RAD;
    const int by0 = blockIdx.y * TILE - RAD;
    const size_t boff = (size_t)blockIdx.z * NC * PLANE;
    const float* __restrict__ xb = x   + boff;
    float*       __restrict__ ob = out + boff;

    // ---- stage: one (plane,pixel) per iter: 4 coalesced channel loads -> b128 write
    for (int idx = tid; idx < 4 * PADW * PADW; idx += NTHR) {
        const int p   = idx / (PADW * PADW);
        const int pix = idx - p * (PADW * PADW);
        const int i   = pix / PADW;
        const int j   = pix - i * PADW;
        const int gy  = by0 + i;
        const int gx  = bx0 + j;
        float4 v = {0.f, 0.f, 0.f, 0.f};
        if ((unsigned)gy < (unsigned)HW && (unsigned)gx < (unsigned)HW) {
            const float* g = xb + (size_t)(4 * p) * PLANE + gy * HW + gx;
            v.x = g[0 * PLANE];
            v.y = g[1 * PLANE];
            v.z = g[2 * PLANE];
            v.w = g[3 * PLANE];
        }
        sm[p][i][j] = v;
    }
    __syncthreads();

    // ---- per-pixel squared norms
    for (int idx = tid; idx < PADW * PADW; idx += NTHR) {
        const int i = idx / PADW;
        const int j = idx - i * PADW;
        const float4 a = sm[0][i][j];
        const float4 b = sm[1][i][j];
        const float4 c = sm[2][i][j];
        const float4 d = sm[3][i][j];
        float nn = 0.f;
        DOT4(nn, a, a); DOT4(nn, b, b); DOT4(nn, c, c); DOT4(nn, d, d);
        smn[i][j] = nn;
    }
    __syncthreads();

    // ---- own pixels (2 adjacent in x) ----
    const int r0 = ty + RAD;
    const int c0 = 2 * tx + RAD;
    const float4 o00 = sm[0][r0][c0],     o01 = sm[1][r0][c0];
    const float4 o02 = sm[2][r0][c0],     o03 = sm[3][r0][c0];
    const float4 o10 = sm[0][r0][c0 + 1], o11 = sm[1][r0][c0 + 1];
    const float4 o12 = sm[2][r0][c0 + 1], o13 = sm[3][r0][c0 + 1];
    const float baseE0 = CEXP * smn[r0][c0];
    const float baseE1 = CEXP * smn[r0][c0 + 1];

    float4 a00 = {0,0,0,0}, a01 = {0,0,0,0}, a02 = {0,0,0,0}, a03 = {0,0,0,0};
    float4 a10 = {0,0,0,0}, a11 = {0,0,0,0}, a12 = {0,0,0,0}, a13 = {0,0,0,0};
    float ws0 = 0.f, ws1 = 0.f;

    for (int dy = 0; dy < KS; ++dy) {
        const int iy = ty + dy;
#pragma unroll
        for (int j = 0; j < 8; ++j) {
            const int jx = 2 * tx + j;
            const float4 n0 = sm[0][iy][jx];
            const float4 n1 = sm[1][iy][jx];
            const float4 n2 = sm[2][iy][jx];
            const float4 n3 = sm[3][iy][jx];
            const float nn = smn[iy][jx];
            if (j < 7) {            // pixel0: window cols j=0..6
                float dt = 0.f;
                DOT4(dt, n0, o00); DOT4(dt, n1, o01);
                DOT4(dt, n2, o02); DOT4(dt, n3, o03);
                float arg = fmaf(CEXP, nn, baseE0);
                arg = fmaf(M2CEXP, dt, arg);    // CEXP*(nn+oo-2*dot)
                const float w = __expf(arg);
                ws0 += w;
                ACC4(a00, n0, w); ACC4(a01, n1, w);
                ACC4(a02, n2, w); ACC4(a03, n3, w);
            }
            if (j > 0) {            // pixel1: window cols j=1..7
                float dt = 0.f;
                DOT4(dt, n0, o10); DOT4(dt, n1, o11);
                DOT4(dt, n2, o12); DOT4(dt, n3, o13);
                float arg = fmaf(CEXP, nn, baseE1);
                arg = fmaf(M2CEXP, dt, arg);
                const float w = __expf(arg);
                ws1 += w;
                ACC4(a10, n0, w); ACC4(a11, n1, w);
                ACC4(a12, n2, w); ACC4(a13, n3, w);
            }
        }
    }

    // ---- epilogue: out = x + RATIO*(acc/wsum - x), float2 store per channel
    const float inv0 = 1.f / ws0;       // wsum >= 1 (center weight = 1)
    const float inv1 = 1.f / ws1;
    const int gy  = blockIdx.y * TILE + ty;
    const int gxp = blockIdx.x * TILE + 2 * tx;     // even -> 8B aligned
    float* base = ob + gy * HW + gxp;

#define STORE1(c, e, A0, A1, O0, O1)                        \
    do {                                                    \
        float2 r;                                           \
        r.x = fmaf(RATIO, (A0).e * inv0 - (O0).e, (O0).e);  \
        r.y = fmaf(RATIO, (A1).e * inv1 - (O1).e, (O1).e);  \
        *(float2*)(base + (c) * PLANE) = r;                 \
    } while (0)

    STORE1( 0, x, a00, a10, o00, o10);
    STORE1( 1, y, a00, a10, o00, o10);
    STORE1( 2, z, a00, a10, o00, o10);
    STORE1( 3, w, a00, a10, o00, o10);
    STORE1( 4, x, a01, a11, o01, o11);
    STORE1( 5, y, a01, a11, o01, o11);
    STORE1( 6, z, a01, a11, o01, o11);
    STORE1( 7, w, a01, a11, o01, o11);
    STORE1( 8, x, a02, a12, o02, o12);
    STORE1( 9, y, a02, a12, o02, o12);
    STORE1(10, z, a02, a12, o02, o12);
    STORE1(11, w, a02, a12, o02, o12);
    STORE1(12, x, a03, a13, o03, o13);
    STORE1(13, y, a03, a13, o03, o13);
    STORE1(14, z, a03, a13, o03, o13);
    STORE1(15, w, a03, a13, o03, o13);
#undef STORE1
}

extern "C" void kernel_launch(void* const* d_in, const int* in_sizes, int n_in,
                              void* d_out, int out_size, void* d_ws, size_t ws_size,
                              hipStream_t stream)
{
    (void)in_sizes; (void)n_in; (void)d_ws; (void)ws_size; (void)out_size;
    const float* x = (const float*)d_in[0];
    float* out = (float*)d_out;

    dim3 block(TXD, TYD, 1);                 // 128 threads = 2 waves
    dim3 grid(HW / TILE, HW / TILE, 2);      // (16,16,2) = 512 blocks
    nlm_kernel<<<grid, block, 0, stream>>>(x, out);
}

// Round 4
// 74.398 us; speedup vs baseline: 1.1182x; 1.1182x over previous
//
#include <hip/hip_runtime.h>

#define RAD   3
#define KS    7
#define TILE  16
#define NTHR  256                  // 16x16 threads, 1 px/thread, 4 waves
#define PADW  (TILE + 2 * RAD)     // 22
#define PADS  23                   // padded row stride (odd -> bank spread)
#define NC    16
#define HW    256
#define PLANE (HW * HW)

// w = exp(-mean_c(d^2)/H2) = exp(CEXP * ss), ss = sum_c d^2, H2 = 0.01
#define CEXP   (-6.25f)            // -1/(16*0.01)
#define RATIO  0.2f
#define SKIPTH (-87.0f)            // exp(arg<=-87) == 0.0f exactly (underflow)

// ss += sum((n-o)^2) over 4 lanes of a float4
#define DIFF4(ss, n, o) do {                          \
    float d_;                                         \
    d_ = (n).x - (o).x; ss = fmaf(d_, d_, ss);        \
    d_ = (n).y - (o).y; ss = fmaf(d_, d_, ss);        \
    d_ = (n).z - (o).z; ss = fmaf(d_, d_, ss);        \
    d_ = (n).w - (o).w; ss = fmaf(d_, d_, ss); } while (0)

#define ACC4(a, n, w) do {            \
    (a).x = fmaf(w, (n).x, (a).x);    \
    (a).y = fmaf(w, (n).y, (a).y);    \
    (a).z = fmaf(w, (n).z, (a).z);    \
    (a).w = fmaf(w, (n).w, (a).w); } while (0)

__global__ __launch_bounds__(NTHR, 2)
void nlm_kernel(const float* __restrict__ x, float* __restrict__ out)
{
    // channel-plane float4 layout; row stride 23 (odd) so row-to-row bank
    // offsets rotate; within a row, 16 lanes x 16B = 2-way aliasing (free).
    __shared__ float4 sm[4][PADW][PADS];   // 32384 B

    const int tx  = threadIdx.x;           // 0..15
    const int ty  = threadIdx.y;           // 0..15
    const int tid = ty * TILE + tx;
    const int bx0 = blockIdx.x * TILE - RAD;
    const int by0 = blockIdx.y * TILE - RAD;
    const size_t boff = (size_t)blockIdx.z * NC * PLANE;
    const float* __restrict__ xb = x   + boff;
    float*       __restrict__ ob = out + boff;

    // ---- stage: one (plane,pixel) per iter: 4 coalesced channel loads -> b128 write
    for (int idx = tid; idx < 4 * PADW * PADW; idx += NTHR) {
        const int p   = idx / (PADW * PADW);
        const int pix = idx - p * (PADW * PADW);
        const int i   = pix / PADW;
        const int j   = pix - i * PADW;
        const int gy  = by0 + i;
        const int gx  = bx0 + j;
        float4 v = {0.f, 0.f, 0.f, 0.f};
        if ((unsigned)gy < (unsigned)HW && (unsigned)gx < (unsigned)HW) {
            const float* g = xb + (size_t)(4 * p) * PLANE + gy * HW + gx;
            v.x = g[0 * PLANE];
            v.y = g[1 * PLANE];
            v.z = g[2 * PLANE];
            v.w = g[3 * PLANE];
        }
        sm[p][i][j] = v;
    }
    __syncthreads();

    // ---- own pixel ----
    const int r0 = ty + RAD;
    const int c0 = tx + RAD;
    const float4 o0 = sm[0][r0][c0];
    const float4 o1 = sm[1][r0][c0];
    const float4 o2 = sm[2][r0][c0];
    const float4 o3 = sm[3][r0][c0];

    float4 a0 = {0,0,0,0}, a1 = {0,0,0,0}, a2 = {0,0,0,0}, a3 = {0,0,0,0};
    float wsum = 0.f;

    for (int dy = 0; dy < KS; ++dy) {
        const int iy = ty + dy;
#pragma unroll
        for (int dx = 0; dx < KS; ++dx) {
            const int jx = tx + dx;
            const float4 n0 = sm[0][iy][jx];
            const float4 n1 = sm[1][iy][jx];
            const float4 n2 = sm[2][iy][jx];
            const float4 n3 = sm[3][iy][jx];
            float ss = 0.f;
            DIFF4(ss, n0, o0); DIFF4(ss, n1, o1);
            DIFF4(ss, n2, o2); DIFF4(ss, n3, o3);
            const float arg = CEXP * ss;
            // exp underflows to exactly 0 below ~-87.3: whole-wave skip is bit-exact.
            if (__any(arg > SKIPTH)) {
                const float w = __expf(arg);
                wsum += w;
                ACC4(a0, n0, w); ACC4(a1, n1, w);
                ACC4(a2, n2, w); ACC4(a3, n3, w);
            }
        }
    }

    // ---- epilogue: out = x + RATIO*(acc/wsum - x) ----
    const float inv = 1.f / wsum;       // wsum >= 1 (center weight == 1 exactly)
    const int gy = blockIdx.y * TILE + ty;
    const int gx = blockIdx.x * TILE + tx;
    float* p = ob + gy * HW + gx;

#define STORE1(c, A, O, e) \
    p[(c) * PLANE] = fmaf(RATIO, (A).e * inv - (O).e, (O).e)

    STORE1( 0, a0, o0, x); STORE1( 1, a0, o0, y);
    STORE1( 2, a0, o0, z); STORE1( 3, a0, o0, w);
    STORE1( 4, a1, o1, x); STORE1( 5, a1, o1, y);
    STORE1( 6, a1, o1, z); STORE1( 7, a1, o1, w);
    STORE1( 8, a2, o2, x); STORE1( 9, a2, o2, y);
    STORE1(10, a2, o2, z); STORE1(11, a2, o2, w);
    STORE1(12, a3, o3, x); STORE1(13, a3, o3, y);
    STORE1(14, a3, o3, z); STORE1(15, a3, o3, w);
#undef STORE1
}

extern "C" void kernel_launch(void* const* d_in, const int* in_sizes, int n_in,
                              void* d_out, int out_size, void* d_ws, size_t ws_size,
                              hipStream_t stream)
{
    (void)in_sizes; (void)n_in; (void)d_ws; (void)ws_size; (void)out_size;
    const float* x = (const float*)d_in[0];
    float* out = (float*)d_out;

    dim3 block(TILE, TILE, 1);               // 256 threads = 4 waves
    dim3 grid(HW / TILE, HW / TILE, 2);      // (16,16,2) = 512 blocks = 2/CU
    nlm_kernel<<<grid, block, 0, stream>>>(x, out);
}